// Round 1
// baseline (90479.913 us; speedup 1.0000x reference)
//
#include <hip/hip_runtime.h>

#define NB 512      // blocks (2 per CU)
#define NT 256      // threads (4 waves)
#define HD 2048
#define IND 1024
#define TS 512

struct Params {
  const float* features;
  const float* eps;
  const float* fW[11];   // fp32 weight sources
  const void*  W[11];    // working weights (bf16 in ws, or == fW)
  const float* bih0e; const float* bhh0e;
  const float* bih1e; const float* bhh1e;
  const float* bmu;   const float* bvar;
  const float* bih0d; const float* bhh0d;
  const float* bih1d; const float* bhh1d;
  const float* bout;
  float* out;
  float* act;
  unsigned* bar;
};

// weight order: 0 Wih0e 1 Whh0e 2 Wih1e 3 Whh1e 4 Wmu 5 Wvar 6 Wih0d 7 Whh0d 8 Wih1d 9 Whh1d 10 Wout
__device__ __constant__ size_t kWSizes[11] = {
  8388608ull,16777216ull,16777216ull,16777216ull,4194304ull,4194304ull,
  16777216ull,16777216ull,16777216ull,16777216ull,2097152ull };

__device__ __forceinline__ float4 w4(const unsigned short* w) {
  uint2 v = *(const uint2*)w;
  float4 r;
  r.x = __uint_as_float(v.x << 16);
  r.y = __uint_as_float(v.x & 0xFFFF0000u);
  r.z = __uint_as_float(v.y << 16);
  r.w = __uint_as_float(v.y & 0xFFFF0000u);
  return r;
}
__device__ __forceinline__ float4 w4(const float* w) { return *(const float4*)w; }

__device__ __forceinline__ unsigned pk(float lo, float hi) {
  unsigned a = __float_as_uint(lo), b = __float_as_uint(hi);
  a = (a + 0x7FFFu + ((a >> 16) & 1u)) >> 16;  // RNE to bf16
  b = (b + 0x7FFFu + ((b >> 16) & 1u)) >> 16;
  return a | (b << 16);
}

__device__ __forceinline__ float wred(float v) {
  v += __shfl_xor(v, 1);  v += __shfl_xor(v, 2);  v += __shfl_xor(v, 4);
  v += __shfl_xor(v, 8);  v += __shfl_xor(v, 16); v += __shfl_xor(v, 32);
  return v;
}

__device__ __forceinline__ float sigm(float x) { return 1.f / (1.f + __expf(-x)); }

// 4 consecutive rows of W (row length K) dotted with xs (LDS), accumulate into acc[4]
template<typename WT>
__device__ __forceinline__ void dot4(const WT* __restrict__ W, int K,
                                     const float* __restrict__ xs, int lane, float acc[4]) {
  for (int k = lane * 4; k < K; k += 256) {
    float4 xv = *(const float4*)(xs + k);
#pragma unroll
    for (int r = 0; r < 4; ++r) {
      float4 wv = w4(W + (size_t)r * K + k);
      acc[r] = fmaf(wv.x, xv.x, fmaf(wv.y, xv.y, fmaf(wv.z, xv.z, fmaf(wv.w, xv.w, acc[r]))));
    }
  }
}

// grid barrier: sense via generation counter, agent (device) scope for cross-XCD
__device__ __forceinline__ void gsync(unsigned* bar) {
  __syncthreads();
  if (threadIdx.x == 0) {
    __threadfence();
    unsigned* cnt = bar;
    unsigned* gen = bar + 32;
    unsigned g = __hip_atomic_load(gen, __ATOMIC_RELAXED, __HIP_MEMORY_SCOPE_AGENT);
    unsigned a = __hip_atomic_fetch_add(cnt, 1u, __ATOMIC_ACQ_REL, __HIP_MEMORY_SCOPE_AGENT);
    if (a == gridDim.x - 1) {
      __hip_atomic_store(cnt, 0u, __ATOMIC_RELAXED, __HIP_MEMORY_SCOPE_AGENT);
      __hip_atomic_fetch_add(gen, 1u, __ATOMIC_RELEASE, __HIP_MEMORY_SCOPE_AGENT);
    } else {
      while (__hip_atomic_load(gen, __ATOMIC_ACQUIRE, __HIP_MEMORY_SCOPE_AGENT) == g) {
        __builtin_amdgcn_s_sleep(2);
      }
    }
  }
  __syncthreads();
}

// One LSTM cell phase. Block owns j0..j0+3 hidden units; wave w computes gate w's 4 rows.
// Optionally also computes 2 rows of Wout @ x (decoder output fusion, reads same xs).
template<typename WT>
__device__ void cell_phase(const WT* __restrict__ Wih, const WT* __restrict__ Whh,
                           const float* __restrict__ bih, const float* __restrict__ bhh,
                           const float* __restrict__ xg, int Kx,
                           const float* __restrict__ hg,
                           float* __restrict__ hout, float* __restrict__ cbuf,
                           const WT* __restrict__ Wo, const float* __restrict__ bo,
                           float* __restrict__ odst,
                           float* lds) {
  const int tid = threadIdx.x;
  float* xs  = lds;
  float* hs  = lds + Kx;
  float* gld = lds + Kx + HD;
  for (int i = tid * 4; i < Kx; i += NT * 4) *(float4*)(xs + i) = *(const float4*)(xg + i);
  for (int i = tid * 4; i < HD; i += NT * 4) *(float4*)(hs + i) = *(const float4*)(hg + i);
  __syncthreads();
  const int wave = tid >> 6, lane = tid & 63;
  const int j0 = blockIdx.x * 4;
  const size_t row0 = (size_t)wave * HD + j0;
  float acc[4] = {0.f, 0.f, 0.f, 0.f};
  dot4(Wih + row0 * (size_t)Kx, Kx, xs, lane, acc);
  dot4(Whh + row0 * (size_t)HD, HD, hs, lane, acc);
#pragma unroll
  for (int r = 0; r < 4; ++r) {
    float s = wred(acc[r]);
    if (lane == 0) gld[wave * 4 + r] = s;
  }
  if (Wo != nullptr && wave < 2) {
    const int row = blockIdx.x * 2 + wave;
    const WT* wr = Wo + (size_t)row * HD;
    float a = 0.f;
    for (int k = lane * 4; k < HD; k += 256) {
      float4 wv = w4(wr + k);
      float4 xv = *(const float4*)(xs + k);
      a = fmaf(wv.x, xv.x, fmaf(wv.y, xv.y, fmaf(wv.z, xv.z, fmaf(wv.w, xv.w, a))));
    }
    a = wred(a);
    if (lane == 0) odst[row] = a + bo[row];
  }
  __syncthreads();
  if (tid < 4) {
    const int j = j0 + tid;
    float gi = gld[tid]      + bih[j]          + bhh[j];
    float gf = gld[4 + tid]  + bih[HD + j]     + bhh[HD + j];
    float gc = gld[8 + tid]  + bih[2 * HD + j] + bhh[2 * HD + j];
    float go = gld[12 + tid] + bih[3 * HD + j] + bhh[3 * HD + j];
    float c  = cbuf[j];
    float cn = sigm(gf) * c + sigm(gi) * tanhf(gc);
    float hn = sigm(go) * tanhf(cn);
    cbuf[j] = cn;
    hout[j] = hn;
  }
}

__global__ void init_kernel(unsigned* bar, float* act) {
  const int t = threadIdx.x;
  if (t < 64) bar[t] = 0u;
  for (int i = t; i < 30720; i += 256) act[i] = 0.f;
}

template<typename WT>
__global__ __launch_bounds__(NT, 2) void vae_kernel(Params p) {
  __shared__ float lds[2 * HD + 64];
  const int tid = threadIdx.x;
  float* act = p.act;
  float* h0b = act;                 // 2*HD (parity buffers)
  float* c0  = act + 4096;
  float* h1b = act + 6144;          // 2*HD
  float* c1  = act + 10240;
  float* dh0 = act + 12288;         // 2*HD
  float* dh1 = act + 16384;         // 2*HD
  float* mu  = act + 20480;         // 4096
  float* sp  = act + 24576;         // 4096
  float* zb  = act + 28672;         // 2048 zeros

  // ---- phase 0: convert weights fp32 -> bf16 into ws (skip Wmu/Wvar: kept fp32) ----
  if constexpr (sizeof(WT) == 2) {
    const size_t gsz = (size_t)gridDim.x * NT;
    const size_t g0  = (size_t)blockIdx.x * NT + tid;
    for (int m = 0; m < 11; ++m) {
      if (m == 4 || m == 5) continue;
      const float* s = p.fW[m];
      unsigned short* d = (unsigned short*)p.W[m];
      const size_t n = kWSizes[m];
      for (size_t i = g0 * 8; i < n; i += gsz * 8) {
        float4 a = *(const float4*)(s + i);
        float4 b = *(const float4*)(s + i + 4);
        uint4 o;
        o.x = pk(a.x, a.y); o.y = pk(a.z, a.w);
        o.z = pk(b.x, b.y); o.w = pk(b.z, b.w);
        *(uint4*)(d + i) = o;
      }
    }
  }
  gsync(p.bar);

  const WT* Wih0e = (const WT*)p.W[0];
  const WT* Whh0e = (const WT*)p.W[1];
  const WT* Wih1e = (const WT*)p.W[2];
  const WT* Whh1e = (const WT*)p.W[3];
  const WT* Wih0d = (const WT*)p.W[6];
  const WT* Whh0d = (const WT*)p.W[7];
  const WT* Wih1d = (const WT*)p.W[8];
  const WT* Whh1d = (const WT*)p.W[9];
  const WT* Wout  = (const WT*)p.W[10];

  // ---- encoder: 512 steps x 2 cells ----
  for (int t = 0; t < TS; ++t) {
    cell_phase(Wih0e, Whh0e, p.bih0e, p.bhh0e,
               p.features + (size_t)t * IND, IND,
               h0b + (t & 1) * HD, h0b + ((t + 1) & 1) * HD, c0,
               (const WT*)nullptr, (const float*)nullptr, (float*)nullptr, lds);
    gsync(p.bar);
    cell_phase(Wih1e, Whh1e, p.bih1e, p.bhh1e,
               h0b + ((t + 1) & 1) * HD, HD,
               h1b + (t & 1) * HD, h1b + ((t + 1) & 1) * HD, c1,
               (const WT*)nullptr, (const float*)nullptr, (float*)nullptr, lds);
    gsync(p.bar);
  }
  // final h0 = h0b[0], h1 = h1b[0] (last write parity (511+1)&1 == 0)

  // ---- latent: blocks 0..255 -> mu rows, 256..511 -> var rows (fp32 weights) ----
  {
    const int b = blockIdx.x;
    const bool isVar = b >= 256;
    const int u0 = (isVar ? b - 256 : b) * 16;
    const int s  = u0 >> 11;
    const int i0 = u0 & 2047;
    const float* hsrc = s ? h1b : h0b;
    float* xs = lds;
    for (int i = tid * 4; i < HD; i += NT * 4) *(float4*)(xs + i) = *(const float4*)(hsrc + i);
    __syncthreads();
    const float* Wl = isVar ? p.fW[5] : p.fW[4];
    const int wave = tid >> 6, lane = tid & 63;
    const int ri = i0 + wave * 4;
    float acc[4] = {0.f, 0.f, 0.f, 0.f};
    dot4(Wl + (size_t)ri * HD, HD, xs, lane, acc);
#pragma unroll
    for (int r = 0; r < 4; ++r) {
      float v = wred(acc[r]);
      if (lane == 0) {
        const int i = ri + r;
        if (!isVar) {
          float m = v + p.bmu[i];
          p.out[s * HD + i] = m;
          mu[s * HD + i] = m;
        } else {
          float vv = v + p.bvar[i];
          float spv = (vv > 15.f) ? vv : log1pf(__expf(vv));
          p.out[4096 + s * HD + i] = __logf(spv);
          sp[s * HD + i] = spv;
        }
      }
    }
  }
  gsync(p.bar);

  // ---- z = mu + eps * sqrt(softplus) -> decoder h inits; c0/c1 carried in place ----
  if (blockIdx.x < 16) {
    const int idx = blockIdx.x * NT + tid;  // 0..4095
    const float z = mu[idx] + p.eps[idx] * sqrtf(sp[idx]);
    if (idx < HD) dh0[idx] = z;
    else          dh1[idx - HD] = z;
  }
  gsync(p.bar);

  // ---- decoder: 512 steps; out_{t-1} fused into phase A (same x = dh1_{t-1}) ----
  for (int t = 0; t < TS; ++t) {
    const float* xdec = t ? (dh1 + (t & 1) * HD) : zb;
    cell_phase(Wih0d, Whh0d, p.bih0d, p.bhh0d,
               xdec, HD,
               dh0 + (t & 1) * HD, dh0 + ((t + 1) & 1) * HD, c0,
               t ? Wout : (const WT*)nullptr, p.bout,
               p.out + 8192 + (size_t)(512 - t) * IND, lds);
    gsync(p.bar);
    cell_phase(Wih1d, Whh1d, p.bih1d, p.bhh1d,
               dh0 + ((t + 1) & 1) * HD, HD,
               dh1 + (t & 1) * HD, dh1 + ((t + 1) & 1) * HD, c1,
               (const WT*)nullptr, (const float*)nullptr, (float*)nullptr, lds);
    gsync(p.bar);
  }

  // ---- final out_511 -> decoded index 0; x = dh1[0] ----
  {
    float* xs = lds;
    const float* xg = dh1;  // parity 0
    for (int i = tid * 4; i < HD; i += NT * 4) *(float4*)(xs + i) = *(const float4*)(xg + i);
    __syncthreads();
    const int wave = tid >> 6, lane = tid & 63;
    if (wave < 2) {
      const int row = blockIdx.x * 2 + wave;
      const WT* wr = Wout + (size_t)row * HD;
      float a = 0.f;
      for (int k = lane * 4; k < HD; k += 256) {
        float4 wv = w4(wr + k);
        float4 xv = *(const float4*)(xs + k);
        a = fmaf(wv.x, xv.x, fmaf(wv.y, xv.y, fmaf(wv.z, xv.z, fmaf(wv.w, xv.w, a))));
      }
      a = wred(a);
      if (lane == 0) p.out[8192 + row] = a + p.bout[row];
    }
  }
}

extern "C" void kernel_launch(void* const* d_in, const int* in_sizes, int n_in,
                              void* d_out, int out_size, void* d_ws, size_t ws_size,
                              hipStream_t stream) {
  (void)in_sizes; (void)n_in; (void)out_size;
  Params p;
  p.features = (const float*)d_in[0];
  p.eps      = (const float*)d_in[1];
  const int wIdx[11] = {2, 3, 6, 7, 10, 12, 14, 15, 18, 19, 22};
  static const size_t wsizes[11] = {
    8388608ull,16777216ull,16777216ull,16777216ull,4194304ull,4194304ull,
    16777216ull,16777216ull,16777216ull,16777216ull,2097152ull };
  for (int m = 0; m < 11; ++m) p.fW[m] = (const float*)d_in[wIdx[m]];
  p.bih0e = (const float*)d_in[4];  p.bhh0e = (const float*)d_in[5];
  p.bih1e = (const float*)d_in[8];  p.bhh1e = (const float*)d_in[9];
  p.bmu   = (const float*)d_in[11]; p.bvar  = (const float*)d_in[13];
  p.bih0d = (const float*)d_in[16]; p.bhh0d = (const float*)d_in[17];
  p.bih1d = (const float*)d_in[20]; p.bhh1d = (const float*)d_in[21];
  p.bout  = (const float*)d_in[23];
  p.out = (float*)d_out;

  char* ws = (char*)d_ws;
  p.bar = (unsigned*)ws;
  p.act = (float*)(ws + 256);
  size_t total = 0;
  for (int m = 0; m < 11; ++m) total += wsizes[m];
  const size_t base = 256 + 131072;
  const bool bf = ws_size >= base + total * 2;
  if (bf) {
    char* wp = ws + base;
    for (int m = 0; m < 11; ++m) { p.W[m] = wp; wp += wsizes[m] * 2; }
  } else {
    for (int m = 0; m < 11; ++m) p.W[m] = p.fW[m];
  }

  init_kernel<<<dim3(1), dim3(256), 0, stream>>>(p.bar, p.act);
  void* args[] = { &p };
  if (bf) {
    hipLaunchCooperativeKernel(reinterpret_cast<void*>(vae_kernel<unsigned short>),
                               dim3(NB), dim3(NT), args, 0, stream);
  } else {
    hipLaunchCooperativeKernel(reinterpret_cast<void*>(vae_kernel<float>),
                               dim3(NB), dim3(NT), args, 0, stream);
  }
}

// Round 2
// 43616.794 us; speedup vs baseline: 2.0744x; 2.0744x over previous
//
#include <hip/hip_runtime.h>

#define NB 512      // blocks (2 per CU)
#define NT 256      // threads (4 waves)
#define HD 2048
#define IND 1024
#define TS 512

// control slots (64B each): 0 genF, 1 genA, 2 genB, 3..514 flagsF, 515..770 flagsA, 771..1026 flagsB
#define SL_GENF 0
#define SL_GENA 1
#define SL_GENB 2
#define SL_FLF  3
#define SL_FLA  (3 + 512)
#define SL_FLB  (3 + 512 + 256)
#define N_SLOTS (3 + 512 + 256 + 256)

struct Params {
  const float* features;
  const float* eps;
  const float* fW[11];   // fp32 weight sources
  const void*  W[11];    // working weights (bf16 in ws, or == fW)
  const float* bih0e; const float* bhh0e;
  const float* bih1e; const float* bhh1e;
  const float* bmu;   const float* bvar;
  const float* bih0d; const float* bhh0d;
  const float* bih1d; const float* bhh1d;
  const float* bout;
  float* out;
  float* act;
  unsigned* ctrl;
};

// weight order: 0 Wih0e 1 Whh0e 2 Wih1e 3 Whh1e 4 Wmu 5 Wvar 6 Wih0d 7 Whh0d 8 Wih1d 9 Whh1d 10 Wout
__device__ __constant__ size_t kWSizes[11] = {
  8388608ull,16777216ull,16777216ull,16777216ull,4194304ull,4194304ull,
  16777216ull,16777216ull,16777216ull,16777216ull,2097152ull };

__device__ __forceinline__ float4 w4(const unsigned short* w) {
  uint2 v = *(const uint2*)w;
  float4 r;
  r.x = __uint_as_float(v.x << 16);
  r.y = __uint_as_float(v.x & 0xFFFF0000u);
  r.z = __uint_as_float(v.y << 16);
  r.w = __uint_as_float(v.y & 0xFFFF0000u);
  return r;
}
__device__ __forceinline__ float4 w4(const float* w) { return *(const float4*)w; }

__device__ __forceinline__ unsigned pk(float lo, float hi) {
  unsigned a = __float_as_uint(lo), b = __float_as_uint(hi);
  a = (a + 0x7FFFu + ((a >> 16) & 1u)) >> 16;  // RNE to bf16
  b = (b + 0x7FFFu + ((b >> 16) & 1u)) >> 16;
  return a | (b << 16);
}

__device__ __forceinline__ float wred(float v) {
  v += __shfl_xor(v, 1);  v += __shfl_xor(v, 2);  v += __shfl_xor(v, 4);
  v += __shfl_xor(v, 8);  v += __shfl_xor(v, 16); v += __shfl_xor(v, 32);
  return v;
}

__device__ __forceinline__ float sigm(float x) { return 1.f / (1.f + __expf(-x)); }

// ---- atomic helpers: relaxed polls read the coherence point WITHOUT cache invalidation;
// ---- exactly one acquire per barrier passage does the L1/L2 invalidate.
__device__ __forceinline__ unsigned ld_rlx(unsigned* p) {
  return __hip_atomic_load(p, __ATOMIC_RELAXED, __HIP_MEMORY_SCOPE_AGENT);
}
__device__ __forceinline__ unsigned ld_acq(unsigned* p) {
  return __hip_atomic_load(p, __ATOMIC_ACQUIRE, __HIP_MEMORY_SCOPE_AGENT);
}
__device__ __forceinline__ void st_rel(unsigned* p, unsigned v) {
  __hip_atomic_store(p, v, __ATOMIC_RELEASE, __HIP_MEMORY_SCOPE_AGENT);
}

// flag-array barrier: parallel release-stores to private slots, leader sweeps with
// relaxed loads, publishes gen; waiters relaxed-poll gen then one acquire.
__device__ __forceinline__ void barrier_sync(unsigned* ctrl, int flags_slot0, int n,
                                             int myidx, bool leader, int gen_slot,
                                             unsigned target) {
  __syncthreads();
  if (threadIdx.x == 0) st_rel(ctrl + (size_t)(flags_slot0 + myidx) * 16, target);
  if (leader) {
    bool done = false;
    while (!done) {
      bool mine = true;
      for (int i = threadIdx.x; i < n; i += NT)
        mine = mine && (ld_rlx(ctrl + (size_t)(flags_slot0 + i) * 16) >= target);
      done = (bool)__syncthreads_and((int)mine);
      if (!done && threadIdx.x == 0) __builtin_amdgcn_s_sleep(1);
    }
    if (threadIdx.x == 0) {
      (void)ld_acq(ctrl + (size_t)flags_slot0 * 16);   // invalidate our caches
      st_rel(ctrl + (size_t)gen_slot * 16, target);
    }
  } else {
    if (threadIdx.x == 0) {
      while (ld_rlx(ctrl + (size_t)gen_slot * 16) < target) __builtin_amdgcn_s_sleep(2);
      (void)ld_acq(ctrl + (size_t)gen_slot * 16);      // single acquire
    }
  }
  __syncthreads();
}

// producer/consumer wait on a generation counter
__device__ __forceinline__ void wait_gen(unsigned* ctrl, int gen_slot, unsigned target) {
  if (threadIdx.x == 0) {
    while (ld_rlx(ctrl + (size_t)gen_slot * 16) < target) __builtin_amdgcn_s_sleep(2);
    (void)ld_acq(ctrl + (size_t)gen_slot * 16);
  }
  __syncthreads();
}

template<typename WT, int U>
__device__ __forceinline__ void dotU(const WT* __restrict__ W, int K,
                                     const float* __restrict__ xs, int lane, float* acc) {
  for (int k = lane * 4; k < K; k += 256) {
    float4 xv = *(const float4*)(xs + k);
#pragma unroll
    for (int r = 0; r < U; ++r) {
      float4 wv = w4(W + (size_t)r * K + k);
      acc[r] = fmaf(wv.x, xv.x, fmaf(wv.y, xv.y, fmaf(wv.z, xv.z, fmaf(wv.w, xv.w, acc[r]))));
    }
  }
}

// One LSTM cell phase. Block owns U hidden units starting at j0; wave w computes gate w's U rows.
// Optionally fuses 2 rows of Wout @ x (decoder output; reads same xs).
template<typename WT, int U>
__device__ void cell_phase(const WT* __restrict__ Wih, const WT* __restrict__ Whh,
                           const float* __restrict__ bih, const float* __restrict__ bhh,
                           const float* __restrict__ xg, int Kx,
                           const float* __restrict__ hg,
                           float* __restrict__ hout, float* __restrict__ cbuf, int j0,
                           const WT* __restrict__ Wo, const float* __restrict__ bo,
                           float* __restrict__ odst, int orow0,
                           float* lds) {
  const int tid = threadIdx.x;
  float* xs  = lds;
  float* hs  = lds + Kx;
  float* gld = lds + Kx + HD;
  for (int i = tid * 4; i < Kx; i += NT * 4) *(float4*)(xs + i) = *(const float4*)(xg + i);
  for (int i = tid * 4; i < HD; i += NT * 4) *(float4*)(hs + i) = *(const float4*)(hg + i);
  __syncthreads();
  const int wave = tid >> 6, lane = tid & 63;
  const size_t row0 = (size_t)wave * HD + j0;
  float acc[U];
#pragma unroll
  for (int r = 0; r < U; ++r) acc[r] = 0.f;
  dotU<WT, U>(Wih + row0 * (size_t)Kx, Kx, xs, lane, acc);
  dotU<WT, U>(Whh + row0 * (size_t)HD, HD, hs, lane, acc);
#pragma unroll
  for (int r = 0; r < U; ++r) {
    float s = wred(acc[r]);
    if (lane == 0) gld[wave * U + r] = s;
  }
  if (Wo != nullptr && wave < 2) {
    const int row = orow0 + wave;
    const WT* wr = Wo + (size_t)row * HD;
    float a = 0.f;
    for (int k = lane * 4; k < HD; k += 256) {
      float4 wv = w4(wr + k);
      float4 xv = *(const float4*)(xs + k);
      a = fmaf(wv.x, xv.x, fmaf(wv.y, xv.y, fmaf(wv.z, xv.z, fmaf(wv.w, xv.w, a))));
    }
    a = wred(a);
    if (lane == 0) odst[row] = a + bo[row];
  }
  __syncthreads();
  if (tid < U) {
    const int j = j0 + tid;
    float gi = gld[0 * U + tid] + bih[j]          + bhh[j];
    float gf = gld[1 * U + tid] + bih[HD + j]     + bhh[HD + j];
    float gc = gld[2 * U + tid] + bih[2 * HD + j] + bhh[2 * HD + j];
    float go = gld[3 * U + tid] + bih[3 * HD + j] + bhh[3 * HD + j];
    float c  = cbuf[j];
    float cn = sigm(gf) * c + sigm(gi) * tanhf(gc);
    float hn = sigm(go) * tanhf(cn);
    cbuf[j] = cn;
    hout[j] = hn;
  }
}

__global__ void init_kernel(unsigned* ctrl, float* act) {
  const int t = threadIdx.x;
  for (int i = t; i < N_SLOTS * 16; i += 256) ctrl[i] = 0u;
  for (int i = t; i < 30720; i += 256) act[i] = 0.f;
}

template<typename WT>
__global__ __launch_bounds__(NT, 2) void vae_kernel(Params p) {
  __shared__ float lds[2 * HD + 64];
  const int tid = threadIdx.x;
  unsigned* ctrl = p.ctrl;
  float* act = p.act;
  float* h0b = act;                 // 2*HD (parity buffers)
  float* c0  = act + 4096;
  float* h1b = act + 6144;          // 2*HD
  float* c1  = act + 10240;
  float* dh0 = act + 12288;         // 2*HD
  float* dh1 = act + 16384;         // 2*HD
  float* mu  = act + 20480;         // 4096
  float* sp  = act + 24576;         // 4096
  float* zb  = act + 28672;         // 2048 zeros

  unsigned gf = 0;

  // ---- phase 0: convert weights fp32 -> bf16 into ws (skip Wmu/Wvar: kept fp32) ----
  if constexpr (sizeof(WT) == 2) {
    const size_t gsz = (size_t)gridDim.x * NT;
    const size_t g0  = (size_t)blockIdx.x * NT + tid;
    for (int m = 0; m < 11; ++m) {
      if (m == 4 || m == 5) continue;
      const float* s = p.fW[m];
      unsigned short* d = (unsigned short*)p.W[m];
      const size_t n = kWSizes[m];
      for (size_t i = g0 * 8; i < n; i += gsz * 8) {
        float4 a = *(const float4*)(s + i);
        float4 b = *(const float4*)(s + i + 4);
        uint4 o;
        o.x = pk(a.x, a.y); o.y = pk(a.z, a.w);
        o.z = pk(b.x, b.y); o.w = pk(b.z, b.w);
        *(uint4*)(d + i) = o;
      }
    }
  }
  ++gf;
  barrier_sync(ctrl, SL_FLF, NB, blockIdx.x, blockIdx.x == 0, SL_GENF, gf);

  const WT* Wih0e = (const WT*)p.W[0];
  const WT* Whh0e = (const WT*)p.W[1];
  const WT* Wih1e = (const WT*)p.W[2];
  const WT* Whh1e = (const WT*)p.W[3];
  const WT* Wih0d = (const WT*)p.W[6];
  const WT* Whh0d = (const WT*)p.W[7];
  const WT* Wih1d = (const WT*)p.W[8];
  const WT* Whh1d = (const WT*)p.W[9];
  const WT* Wout  = (const WT*)p.W[10];

  // ---- encoder: layer0 chain (blocks 0..255) || layer1 chain (blocks 256..511) ----
  // layer0 depends only on features + its own state; layer1 consumes h0 one step behind.
  if (blockIdx.x < 256) {
    const int bb = blockIdx.x;
    for (int t = 0; t < TS; ++t) {
      if (t >= 2) wait_gen(ctrl, SL_GENB, (unsigned)(t - 1));  // parity-buffer throttle
      cell_phase<WT, 8>(Wih0e, Whh0e, p.bih0e, p.bhh0e,
                        p.features + (size_t)t * IND, IND,
                        h0b + (t & 1) * HD, h0b + ((t + 1) & 1) * HD, c0, bb * 8,
                        (const WT*)nullptr, nullptr, nullptr, 0, lds);
      barrier_sync(ctrl, SL_FLA, 256, bb, bb == 0, SL_GENA, (unsigned)(t + 1));
    }
  } else {
    const int bb = blockIdx.x - 256;
    for (int t = 0; t < TS; ++t) {
      wait_gen(ctrl, SL_GENA, (unsigned)(t + 1));              // h0 of step t ready
      cell_phase<WT, 8>(Wih1e, Whh1e, p.bih1e, p.bhh1e,
                        h0b + ((t + 1) & 1) * HD, HD,
                        h1b + (t & 1) * HD, h1b + ((t + 1) & 1) * HD, c1, bb * 8,
                        (const WT*)nullptr, nullptr, nullptr, 0, lds);
      barrier_sync(ctrl, SL_FLB, 256, bb, bb == 0, SL_GENB, (unsigned)(t + 1));
    }
  }
  ++gf;
  barrier_sync(ctrl, SL_FLF, NB, blockIdx.x, blockIdx.x == 0, SL_GENF, gf);
  // final h0 = h0b[0], h1 = h1b[0]

  // ---- latent: blocks 0..255 -> mu rows, 256..511 -> var rows (fp32 weights) ----
  {
    const int b = blockIdx.x;
    const bool isVar = b >= 256;
    const int u0 = (isVar ? b - 256 : b) * 16;
    const int s  = u0 >> 11;
    const int i0 = u0 & 2047;
    const float* hsrc = s ? h1b : h0b;
    float* xs = lds;
    for (int i = tid * 4; i < HD; i += NT * 4) *(float4*)(xs + i) = *(const float4*)(hsrc + i);
    __syncthreads();
    const float* Wl = isVar ? p.fW[5] : p.fW[4];
    const int wave = tid >> 6, lane = tid & 63;
    const int ri = i0 + wave * 4;
    float acc[4] = {0.f, 0.f, 0.f, 0.f};
    dotU<float, 4>(Wl + (size_t)ri * HD, HD, xs, lane, acc);
#pragma unroll
    for (int r = 0; r < 4; ++r) {
      float v = wred(acc[r]);
      if (lane == 0) {
        const int i = ri + r;
        if (!isVar) {
          float m = v + p.bmu[i];
          p.out[s * HD + i] = m;
          mu[s * HD + i] = m;
        } else {
          float vv = v + p.bvar[i];
          float spv = (vv > 15.f) ? vv : log1pf(__expf(vv));
          p.out[4096 + s * HD + i] = __logf(spv);
          sp[s * HD + i] = spv;
        }
      }
    }
  }
  ++gf;
  barrier_sync(ctrl, SL_FLF, NB, blockIdx.x, blockIdx.x == 0, SL_GENF, gf);

  // ---- z = mu + eps * sqrt(softplus) -> decoder h inits ----
  if (blockIdx.x < 16) {
    const int idx = blockIdx.x * NT + tid;  // 0..4095
    const float z = mu[idx] + p.eps[idx] * sqrtf(sp[idx]);
    if (idx < HD) dh0[idx] = z;
    else          dh1[idx - HD] = z;
  }
  ++gf;
  barrier_sync(ctrl, SL_FLF, NB, blockIdx.x, blockIdx.x == 0, SL_GENF, gf);

  // ---- decoder: 512 steps; out_{t-1} fused into phase A (same x = dh1_{t-1}) ----
  for (int t = 0; t < TS; ++t) {
    const float* xdec = t ? (dh1 + (t & 1) * HD) : zb;
    cell_phase<WT, 4>(Wih0d, Whh0d, p.bih0d, p.bhh0d,
                      xdec, HD,
                      dh0 + (t & 1) * HD, dh0 + ((t + 1) & 1) * HD, c0, blockIdx.x * 4,
                      t ? Wout : (const WT*)nullptr, p.bout,
                      p.out + 8192 + (size_t)(512 - t) * IND, blockIdx.x * 2, lds);
    ++gf;
    barrier_sync(ctrl, SL_FLF, NB, blockIdx.x, blockIdx.x == 0, SL_GENF, gf);
    cell_phase<WT, 4>(Wih1d, Whh1d, p.bih1d, p.bhh1d,
                      dh0 + ((t + 1) & 1) * HD, HD,
                      dh1 + (t & 1) * HD, dh1 + ((t + 1) & 1) * HD, c1, blockIdx.x * 4,
                      (const WT*)nullptr, nullptr, nullptr, 0, lds);
    ++gf;
    barrier_sync(ctrl, SL_FLF, NB, blockIdx.x, blockIdx.x == 0, SL_GENF, gf);
  }

  // ---- final out_511 -> decoded index 0; x = dh1[0] ----
  {
    float* xs = lds;
    const float* xg = dh1;  // parity 0
    for (int i = tid * 4; i < HD; i += NT * 4) *(float4*)(xs + i) = *(const float4*)(xg + i);
    __syncthreads();
    const int wave = tid >> 6, lane = tid & 63;
    if (wave < 2) {
      const int row = blockIdx.x * 2 + wave;
      const WT* wr = Wout + (size_t)row * HD;
      float a = 0.f;
      for (int k = lane * 4; k < HD; k += 256) {
        float4 wv = w4(wr + k);
        float4 xv = *(const float4*)(xs + k);
        a = fmaf(wv.x, xv.x, fmaf(wv.y, xv.y, fmaf(wv.z, xv.z, fmaf(wv.w, xv.w, a))));
      }
      a = wred(a);
      if (lane == 0) p.out[8192 + row] = a + p.bout[row];
    }
  }
}

extern "C" void kernel_launch(void* const* d_in, const int* in_sizes, int n_in,
                              void* d_out, int out_size, void* d_ws, size_t ws_size,
                              hipStream_t stream) {
  (void)in_sizes; (void)n_in; (void)out_size;
  Params p;
  p.features = (const float*)d_in[0];
  p.eps      = (const float*)d_in[1];
  const int wIdx[11] = {2, 3, 6, 7, 10, 12, 14, 15, 18, 19, 22};
  static const size_t wsizes[11] = {
    8388608ull,16777216ull,16777216ull,16777216ull,4194304ull,4194304ull,
    16777216ull,16777216ull,16777216ull,16777216ull,2097152ull };
  for (int m = 0; m < 11; ++m) p.fW[m] = (const float*)d_in[wIdx[m]];
  p.bih0e = (const float*)d_in[4];  p.bhh0e = (const float*)d_in[5];
  p.bih1e = (const float*)d_in[8];  p.bhh1e = (const float*)d_in[9];
  p.bmu   = (const float*)d_in[11]; p.bvar  = (const float*)d_in[13];
  p.bih0d = (const float*)d_in[16]; p.bhh0d = (const float*)d_in[17];
  p.bih1d = (const float*)d_in[20]; p.bhh1d = (const float*)d_in[21];
  p.bout  = (const float*)d_in[23];
  p.out = (float*)d_out;

  char* ws = (char*)d_ws;
  p.ctrl = (unsigned*)ws;
  const size_t ctrl_bytes = (size_t)N_SLOTS * 64;         // 65728
  const size_t act_off = (ctrl_bytes + 255) & ~(size_t)255;
  p.act = (float*)(ws + act_off);
  const size_t base = act_off + ((30720 * 4 + 255) & ~(size_t)255);
  size_t total = 0;
  for (int m = 0; m < 11; ++m) total += wsizes[m];
  const bool bf = ws_size >= base + total * 2;
  if (bf) {
    char* wp = ws + base;
    for (int m = 0; m < 11; ++m) { p.W[m] = wp; wp += wsizes[m] * 2; }
  } else {
    for (int m = 0; m < 11; ++m) p.W[m] = p.fW[m];
  }

  init_kernel<<<dim3(1), dim3(256), 0, stream>>>(p.ctrl, p.act);
  void* args[] = { &p };
  if (bf) {
    hipLaunchCooperativeKernel(reinterpret_cast<void*>(vae_kernel<unsigned short>),
                               dim3(NB), dim3(NT), args, 0, stream);
  } else {
    hipLaunchCooperativeKernel(reinterpret_cast<void*>(vae_kernel<float>),
                               dim3(NB), dim3(NT), args, 0, stream);
  }
}